// Round 1
// baseline (913.024 us; speedup 1.0000x reference)
//
#include <hip/hip_runtime.h>

typedef unsigned short u16;
typedef float f32x4 __attribute__((ext_vector_type(4)));
typedef short s16x8 __attribute__((ext_vector_type(8)));

#define NB 32          // batch
#define NC 1024        // channels
#define CI 512         // inter channels
#define NN 784         // spatial positions
#define NPAD 896       // 7*128
#define M3 1536        // 3*CI

// ---- workspace layout (bytes) ----
#define OFF_XBT   0ull                      // bf16 [NB][NPAD][NC]        58,720,256
#define OFF_WCAT  58720256ull               // bf16 [1536][1024]           3,145,728
#define OFF_PROJ  61865984ull               // bf16 [NB][784][1536]+pad   77,119,488
#define OFF_ABAR  138985472ull              // f32  [NB][784]                100,352
#define OFF_XBAR  139085824ull              // f32  [NB][1024]               131,072
#define WS_NEED   139216896ull

__device__ __forceinline__ u16 f2bf(float x) {
    union { float f; unsigned u; } v; v.f = x;
    unsigned r = v.u + 0x7fffu + ((v.u >> 16) & 1u);
    return (u16)(r >> 16);
}
__device__ __forceinline__ float bf2f(u16 h) {
    union { unsigned u; float f; } v; v.u = ((unsigned)h) << 16;
    return v.f;
}
__device__ __forceinline__ void gload16(const u16* g, u16* l) {
    __builtin_amdgcn_global_load_lds(
        (const __attribute__((address_space(1))) unsigned int*)(const void*)g,
        (__attribute__((address_space(3))) unsigned int*)(void*)l,
        16, 0, 0);
}
__device__ __forceinline__ float wred_sum(float s) {
    #pragma unroll
    for (int o = 32; o; o >>= 1) s += __shfl_xor(s, o);
    return s;
}

// ---- K0a: cast the three projection weights into one bf16 [1536][1024] ----
__global__ void k_cast_w(const float* __restrict__ Wth, const float* __restrict__ Wph,
                         const float* __restrict__ Wg, u16* __restrict__ Wcat) {
    int T = blockIdx.x * 256 + threadIdx.x;
    int e = T * 4;
    int row = e >> 10, col = e & 1023;
    const float* src = (row < 512) ? (Wth + (size_t)row * 1024)
                     : (row < 1024) ? (Wph + (size_t)(row - 512) * 1024)
                                    : (Wg + (size_t)(row - 1024) * 1024);
    float4 v = *(const float4*)(src + col);
    ushort4 o;
    o.x = f2bf(v.x); o.y = f2bf(v.y); o.z = f2bf(v.z); o.w = f2bf(v.w);
    *(ushort4*)(Wcat + e) = o;
}

// ---- K0b: transpose-cast x_body [b][c][n] f32 -> xbT [b][n][c] bf16, + xbar sums ----
__global__ void k_tcast(const float* __restrict__ xb, u16* __restrict__ xbT,
                        float* __restrict__ xbar) {
    __shared__ float tile[32][33];
    int b = blockIdx.z, c0 = blockIdx.y * 32, n0 = blockIdx.x * 32;
    int t = threadIdx.x, j = t & 31, r0 = t >> 5;
    const float* xp = xb + ((size_t)b * NC + c0) * NN;
    #pragma unroll
    for (int rr = r0; rr < 32; rr += 8) {
        int n = n0 + j;
        tile[rr][j] = (n < NN) ? xp[(size_t)rr * NN + n] : 0.f;
    }
    __syncthreads();
    if (t < 32) {
        float s = 0.f;
        #pragma unroll
        for (int q = 0; q < 32; ++q) s += tile[t][q];
        atomicAdd(&xbar[b * NC + c0 + t], s);
    }
    #pragma unroll
    for (int rr = r0; rr < 32; rr += 8) {
        int n = n0 + rr;
        if (n < NN) xbT[((size_t)b * NPAD + n)* NC + c0 + j] = f2bf(tile[j][rr]);
    }
}

// ---- K1: projections GEMM. OUT[b][n][m] = sum_k xbT[b][n][k]*Wcat[m][k] + bias[m]
// m 0..511 = theta, 512..1023 = phi^T, 1024..1535 = g^T. 128x128 tile, BK=32. ----
__global__ __launch_bounds__(256) void k_gemm(
        const u16* __restrict__ xbT, const u16* __restrict__ Wcat,
        const float* __restrict__ bth, const float* __restrict__ bph,
        const float* __restrict__ bg, u16* __restrict__ proj) {
    __shared__ u16 At[128 * 32];
    __shared__ u16 Bt[128 * 32];
    int b = blockIdx.z, nt = blockIdx.x, mt = blockIdx.y;
    int t = threadIdx.x, w = t >> 6, l = t & 63;
    int wn = w & 1, wm = w >> 1;
    const u16* Ag = xbT + (size_t)b * NPAD * NC + (size_t)nt * 128 * NC;
    const u16* Bg = Wcat + (size_t)mt * 128 * NC;
    int lrow = l >> 2;                       // row within 16-row segment
    int cg = ((l & 3) ^ ((l >> 3) & 3)) * 8; // pre-swizzled global k-chunk (elems)
    int lc = l & 15, lr = l >> 4;
    int sA = (lr ^ ((lc >> 1) & 3)) * 8;     // swizzled LDS read slot (elems)
    f32x4 acc[4][4] = {};
    for (int kt = 0; kt < 32; ++kt) {
        int k0 = kt * 32;
        int s0 = w * 2, s1 = w * 2 + 1;
        gload16(Ag + (size_t)(s0 * 16 + lrow) * NC + k0 + cg, At + s0 * 512);
        gload16(Ag + (size_t)(s1 * 16 + lrow) * NC + k0 + cg, At + s1 * 512);
        gload16(Bg + (size_t)(s0 * 16 + lrow) * NC + k0 + cg, Bt + s0 * 512);
        gload16(Bg + (size_t)(s1 * 16 + lrow) * NC + k0 + cg, Bt + s1 * 512);
        __syncthreads();   // drains vmcnt + barrier
        s16x8 af[4], bf_[4];
        #pragma unroll
        for (int i = 0; i < 4; ++i)
            af[i] = *(const s16x8*)&At[(wn * 64 + i * 16 + lc) * 32 + sA];
        #pragma unroll
        for (int jj = 0; jj < 4; ++jj)
            bf_[jj] = *(const s16x8*)&Bt[(wm * 64 + jj * 16 + lc) * 32 + sA];
        #pragma unroll
        for (int i = 0; i < 4; ++i)
            #pragma unroll
            for (int jj = 0; jj < 4; ++jj)
                acc[i][jj] = __builtin_amdgcn_mfma_f32_16x16x32_bf16(af[i], bf_[jj], acc[i][jj], 0, 0, 0);
        __syncthreads();
    }
    size_t ob = (size_t)b * NN * M3;
    #pragma unroll
    for (int jj = 0; jj < 4; ++jj) {
        int m = mt * 128 + wm * 64 + jj * 16 + lc;
        float bv = (m < 512) ? bth[m] : (m < 1024) ? bph[m - 512] : bg[m - 1024];
        #pragma unroll
        for (int i = 0; i < 4; ++i) {
            int nbase = nt * 128 + wn * 64 + i * 16 + lr * 4;
            #pragma unroll
            for (int r = 0; r < 4; ++r) {
                int n = nbase + r;
                if (n < NN) proj[ob + (size_t)n * M3 + m] = f2bf(acc[i][jj][r] + bv);
            }
        }
    }
}

// ---- K2: attention logits + softmax + column sums into abar ----
__global__ __launch_bounds__(256) void k_attn(const u16* __restrict__ proj,
                                              float* __restrict__ abar) {
    extern __shared__ char smem[];
    u16* th   = (u16*)smem;                    // [32][520] bf16 (pad 8)
    float* S  = (float*)(smem + 33280);        // [32][788] f32  (pad 4)
    float* rmax = (float*)(smem + 134144);     // [32]
    float* rinv = rmax + 32;                   // [32]
    int nb = blockIdx.x, b = blockIdx.y;
    int n0 = nb * 32;
    int t = threadIdx.x, w = t >> 6, l = t & 63;
    const u16* pb = proj + (size_t)b * NN * M3;
    {   // stage theta rows n0..n0+31 (reads into tail pad for the last block)
        int row = t >> 3, kb = (t & 7) * 64;
        const u16* src = pb + (size_t)(n0 + row) * M3 + kb;
        u16* dst = th + row * 520 + kb;
        #pragma unroll
        for (int q = 0; q < 8; ++q) *(s16x8*)(dst + q * 8) = *(const s16x8*)(src + q * 8);
    }
    __syncthreads();
    int lc = l & 15, lr = l >> 4, ko = lr * 8;
    for (int mtile = w; mtile < 49; mtile += 4) {
        f32x4 a0 = {0.f, 0.f, 0.f, 0.f}, a1 = {0.f, 0.f, 0.f, 0.f};
        const u16* ph = pb + 512 + (size_t)(mtile * 16 + lc) * M3;  // phi^T row m
        #pragma unroll
        for (int ks = 0; ks < 16; ++ks) {
            s16x8 bfrag = *(const s16x8*)(ph + ks * 32 + ko);
            s16x8 t0 = *(const s16x8*)(th + lc * 520 + ks * 32 + ko);
            s16x8 t1 = *(const s16x8*)(th + (16 + lc) * 520 + ks * 32 + ko);
            a0 = __builtin_amdgcn_mfma_f32_16x16x32_bf16(t0, bfrag, a0, 0, 0, 0);
            a1 = __builtin_amdgcn_mfma_f32_16x16x32_bf16(t1, bfrag, a1, 0, 0, 0);
        }
        int m = mtile * 16 + lc;
        #pragma unroll
        for (int r = 0; r < 4; ++r) {
            S[(lr * 4 + r) * 788 + m]        = a0[r];
            S[(16 + lr * 4 + r) * 788 + m]   = a1[r];
        }
    }
    __syncthreads();
    for (int r = w; r < 32; r += 4) {
        const float* Sr = S + r * 788;
        float mx = -1e30f;
        for (int m = l; m < NN; m += 64) mx = fmaxf(mx, Sr[m]);
        #pragma unroll
        for (int o = 32; o; o >>= 1) mx = fmaxf(mx, __shfl_xor(mx, o));
        float sm = 0.f;
        for (int m = l; m < NN; m += 64) sm += __expf(Sr[m] - mx);
        sm = wred_sum(sm);
        if (l == 0) { rmax[r] = mx; rinv[r] = 1.f / sm; }
    }
    __syncthreads();
    int nvalid = NN - n0; if (nvalid > 32) nvalid = 32;
    for (int m = t; m < NN; m += 256) {
        float cs = 0.f;
        for (int r = 0; r < nvalid; ++r) cs += __expf(S[r * 788 + m] - rmax[r]) * rinv[r];
        atomicAdd(&abar[b * NN + m], cs);
    }
}

// ---- K3: fused head. One block per batch. ----
__global__ __launch_bounds__(256) void k_head(const u16* __restrict__ proj,
        const float* __restrict__ abar, const float* __restrict__ xbar,
        const float* __restrict__ x_face,
        const float* __restrict__ Ww, const float* __restrict__ bw,
        const float* __restrict__ gamma, const float* __restrict__ beta,
        const float* __restrict__ mean, const float* __restrict__ var,
        const float* __restrict__ W1, const float* __restrict__ b1,
        const float* __restrict__ W2, const float* __restrict__ b2,
        float* __restrict__ out) {
    __shared__ float ab[NN], yb[CI], pooled[NC], hh[CI];
    int b = blockIdx.x, t = threadIdx.x, w = t >> 6, l = t & 63;
    for (int m = t; m < NN; m += 256) ab[m] = abar[b * NN + m];
    __syncthreads();
    // ybar[i] = (1/784) * sum_m g^T[m][i]*abar[m]
    const u16* g = proj + (size_t)b * NN * M3 + 1024;
    float y0 = 0.f, y1 = 0.f;
    #pragma unroll 8
    for (int m = 0; m < NN; ++m) {
        float a = ab[m];
        y0 += a * bf2f(g[(size_t)m * M3 + t]);
        y1 += a * bf2f(g[(size_t)m * M3 + 256 + t]);
    }
    yb[t] = y0 * (1.f / 784.f);
    yb[t + 256] = y1 * (1.f / 784.f);
    __syncthreads();
    // pooled[c] = inv*(Ww.ybar + bw) + beta - mean*inv + xbar/784
    for (int c = w; c < NC; c += 4) {
        const float* wr = Ww + (size_t)c * CI;
        float s = 0.f;
        #pragma unroll
        for (int q = 0; q < 8; ++q) s += wr[q * 64 + l] * yb[q * 64 + l];
        s = wred_sum(s);
        if (l == 0) {
            float inv = gamma[c] * rsqrtf(var[c] + 1e-5f);
            pooled[c] = inv * (s + bw[c]) + beta[c] - mean[c] * inv
                      + xbar[b * NC + c] * (1.f / 784.f);
        }
    }
    __syncthreads();
    for (int j = w; j < CI; j += 4) {
        const float* wr = W1 + (size_t)j * NC;
        float s = 0.f;
        #pragma unroll
        for (int q = 0; q < 16; ++q) s += wr[q * 64 + l] * pooled[q * 64 + l];
        s = wred_sum(s);
        if (l == 0) hh[j] = s + b1[j];
    }
    __syncthreads();
    if (w < 2) {
        const float* wr = W2 + (size_t)w * NC;
        float s = 0.f;
        #pragma unroll
        for (int q = 0; q < 16; ++q) {
            int qq = q * 64 + l;
            float cv = (qq < 512) ? hh[qq] : x_face[(size_t)b * 512 + qq - 512];
            s += wr[qq] * cv;
        }
        s = wred_sum(s);
        if (l == 0) out[b * 2 + w] = s + b2[w];
    }
}

extern "C" void kernel_launch(void* const* d_in, const int* in_sizes, int n_in,
                              void* d_out, int out_size, void* d_ws, size_t ws_size,
                              hipStream_t stream) {
    const float* x_body = (const float*)d_in[0];
    const float* x_face = (const float*)d_in[1];
    const float* Wg  = (const float*)d_in[2];
    const float* bg  = (const float*)d_in[3];
    const float* Wth = (const float*)d_in[4];
    const float* bth = (const float*)d_in[5];
    const float* Wph = (const float*)d_in[6];
    const float* bph = (const float*)d_in[7];
    const float* Ww  = (const float*)d_in[8];
    const float* bw  = (const float*)d_in[9];
    const float* gamma = (const float*)d_in[10];
    const float* beta  = (const float*)d_in[11];
    const float* mean  = (const float*)d_in[12];
    const float* var   = (const float*)d_in[13];
    const float* W1 = (const float*)d_in[14];
    const float* b1 = (const float*)d_in[15];
    const float* W2 = (const float*)d_in[16];
    const float* b2 = (const float*)d_in[17];
    (void)in_sizes; (void)n_in; (void)out_size;

    char* ws = (char*)d_ws;
    u16* xbT   = (u16*)(ws + OFF_XBT);
    u16* Wcat  = (u16*)(ws + OFF_WCAT);
    u16* proj  = (u16*)(ws + OFF_PROJ);
    float* abar = (float*)(ws + OFF_ABAR);
    float* xbar = (float*)(ws + OFF_XBAR);

    // zero the atomic accumulators (abar + xbar are contiguous)
    hipMemsetAsync(ws + OFF_ABAR, 0, 100352 + 131072, stream);

    k_cast_w<<<1536, 256, 0, stream>>>(Wth, Wph, Wg, Wcat);
    k_tcast<<<dim3(25, 32, 32), 256, 0, stream>>>(x_body, xbT, xbar);
    k_gemm<<<dim3(7, 12, 32), 256, 0, stream>>>(xbT, Wcat, bth, bph, bg, proj);
    k_attn<<<dim3(25, 32), 256, 134400, stream>>>(proj, abar);
    k_head<<<32, 256, 0, stream>>>(proj, abar, xbar, x_face, Ww, bw,
                                   gamma, beta, mean, var, W1, b1, W2, b2,
                                   (float*)d_out);
}

// Round 2
// 637.579 us; speedup vs baseline: 1.4320x; 1.4320x over previous
//
#include <hip/hip_runtime.h>

typedef unsigned short u16;
typedef float f32x4 __attribute__((ext_vector_type(4)));
typedef short s16x8 __attribute__((ext_vector_type(8)));

#define NB 32          // batch
#define NC 1024        // channels
#define CI 512         // inter channels
#define NN 784         // spatial positions
#define NPAD 896       // 7*128
#define M3 1536        // 3*CI

// ---- workspace layout (bytes) ----
#define OFF_XBT   0ull                      // bf16 [NB][NPAD][NC]        58,720,256
#define OFF_WCAT  58720256ull               // bf16 [1536][1024]           3,145,728
#define OFF_PROJ  61865984ull               // bf16 [NB][784][1536]+pad   77,119,488
#define OFF_ABAR  138985472ull              // f32  [NB][784]                100,352
#define OFF_XBAR  139085824ull              // f32  [NB][1024]               131,072
// reuse of the xbT region after k_gemm no longer needs it:
#define OFF_YBAR  0ull                      // f32 [NB][512]   65,536
#define OFF_POOL  65536ull                  // f32 [NB][1024] 131,072
#define OFF_H     196608ull                 // f32 [NB][512]   65,536

__device__ __forceinline__ u16 f2bf(float x) {
    union { float f; unsigned u; } v; v.f = x;
    unsigned r = v.u + 0x7fffu + ((v.u >> 16) & 1u);
    return (u16)(r >> 16);
}
__device__ __forceinline__ float bf2f(u16 h) {
    union { unsigned u; float f; } v; v.u = ((unsigned)h) << 16;
    return v.f;
}
__device__ __forceinline__ void gload16(const u16* g, u16* l) {
    __builtin_amdgcn_global_load_lds(
        (const __attribute__((address_space(1))) unsigned int*)(const void*)g,
        (__attribute__((address_space(3))) unsigned int*)(void*)l,
        16, 0, 0);
}
__device__ __forceinline__ float wred_sum(float s) {
    #pragma unroll
    for (int o = 32; o; o >>= 1) s += __shfl_xor(s, o);
    return s;
}

// ---- K0a: cast the three projection weights into one bf16 [1536][1024] ----
__global__ void k_cast_w(const float* __restrict__ Wth, const float* __restrict__ Wph,
                         const float* __restrict__ Wg, u16* __restrict__ Wcat) {
    int T = blockIdx.x * 256 + threadIdx.x;
    int e = T * 4;
    int row = e >> 10, col = e & 1023;
    const float* src = (row < 512) ? (Wth + (size_t)row * 1024)
                     : (row < 1024) ? (Wph + (size_t)(row - 512) * 1024)
                                    : (Wg + (size_t)(row - 1024) * 1024);
    float4 v = *(const float4*)(src + col);
    ushort4 o;
    o.x = f2bf(v.x); o.y = f2bf(v.y); o.z = f2bf(v.z); o.w = f2bf(v.w);
    *(ushort4*)(Wcat + e) = o;
}

// ---- K0b: transpose-cast x_body [b][c][n] f32 -> xbT [b][n][c] bf16, + xbar sums ----
__global__ void k_tcast(const float* __restrict__ xb, u16* __restrict__ xbT,
                        float* __restrict__ xbar) {
    __shared__ float tile[32][33];
    int b = blockIdx.z, c0 = blockIdx.y * 32, n0 = blockIdx.x * 32;
    int t = threadIdx.x, j = t & 31, r0 = t >> 5;
    const float* xp = xb + ((size_t)b * NC + c0) * NN;
    #pragma unroll
    for (int rr = r0; rr < 32; rr += 8) {
        int n = n0 + j;
        tile[rr][j] = (n < NN) ? xp[(size_t)rr * NN + n] : 0.f;
    }
    __syncthreads();
    if (t < 32) {
        float s = 0.f;
        #pragma unroll
        for (int q = 0; q < 32; ++q) s += tile[t][q];
        atomicAdd(&xbar[b * NC + c0 + t], s);
    }
    #pragma unroll
    for (int rr = r0; rr < 32; rr += 8) {
        int n = n0 + rr;
        if (n < NN) xbT[((size_t)b * NPAD + n)* NC + c0 + j] = f2bf(tile[j][rr]);
    }
}

// ---- K1: projections GEMM. OUT[b][n][m] = sum_k xbT[b][n][k]*Wcat[m][k] + bias[m]
// m 0..511 = theta, 512..1023 = phi^T, 1024..1535 = g^T. 128x128 tile, BK=32. ----
__global__ __launch_bounds__(256) void k_gemm(
        const u16* __restrict__ xbT, const u16* __restrict__ Wcat,
        const float* __restrict__ bth, const float* __restrict__ bph,
        const float* __restrict__ bg, u16* __restrict__ proj) {
    __shared__ u16 At[128 * 32];
    __shared__ u16 Bt[128 * 32];
    int b = blockIdx.z, nt = blockIdx.x, mt = blockIdx.y;
    int t = threadIdx.x, w = t >> 6, l = t & 63;
    int wn = w & 1, wm = w >> 1;
    const u16* Ag = xbT + (size_t)b * NPAD * NC + (size_t)nt * 128 * NC;
    const u16* Bg = Wcat + (size_t)mt * 128 * NC;
    int lrow = l >> 2;                       // row within 16-row segment
    int cg = ((l & 3) ^ ((l >> 3) & 3)) * 8; // pre-swizzled global k-chunk (elems)
    int lc = l & 15, lr = l >> 4;
    int sA = (lr ^ ((lc >> 1) & 3)) * 8;     // swizzled LDS read slot (elems)
    f32x4 acc[4][4] = {};
    for (int kt = 0; kt < 32; ++kt) {
        int k0 = kt * 32;
        int s0 = w * 2, s1 = w * 2 + 1;
        gload16(Ag + (size_t)(s0 * 16 + lrow) * NC + k0 + cg, At + s0 * 512);
        gload16(Ag + (size_t)(s1 * 16 + lrow) * NC + k0 + cg, At + s1 * 512);
        gload16(Bg + (size_t)(s0 * 16 + lrow) * NC + k0 + cg, Bt + s0 * 512);
        gload16(Bg + (size_t)(s1 * 16 + lrow) * NC + k0 + cg, Bt + s1 * 512);
        __syncthreads();   // drains vmcnt + barrier
        s16x8 af[4], bf_[4];
        #pragma unroll
        for (int i = 0; i < 4; ++i)
            af[i] = *(const s16x8*)&At[(wn * 64 + i * 16 + lc) * 32 + sA];
        #pragma unroll
        for (int jj = 0; jj < 4; ++jj)
            bf_[jj] = *(const s16x8*)&Bt[(wm * 64 + jj * 16 + lc) * 32 + sA];
        #pragma unroll
        for (int i = 0; i < 4; ++i)
            #pragma unroll
            for (int jj = 0; jj < 4; ++jj)
                acc[i][jj] = __builtin_amdgcn_mfma_f32_16x16x32_bf16(af[i], bf_[jj], acc[i][jj], 0, 0, 0);
        __syncthreads();
    }
    size_t ob = (size_t)b * NN * M3;
    #pragma unroll
    for (int jj = 0; jj < 4; ++jj) {
        int m = mt * 128 + wm * 64 + jj * 16 + lc;
        float bv = (m < 512) ? bth[m] : (m < 1024) ? bph[m - 512] : bg[m - 1024];
        #pragma unroll
        for (int i = 0; i < 4; ++i) {
            int nbase = nt * 128 + wn * 64 + i * 16 + lr * 4;
            #pragma unroll
            for (int r = 0; r < 4; ++r) {
                int n = nbase + r;
                if (n < NN) proj[ob + (size_t)n * M3 + m] = f2bf(acc[i][jj][r] + bv);
            }
        }
    }
}

// ---- K2: attention logits + softmax + column sums into abar ----
__global__ __launch_bounds__(256) void k_attn(const u16* __restrict__ proj,
                                              float* __restrict__ abar) {
    extern __shared__ char smem[];
    u16* th   = (u16*)smem;                    // [32][520] bf16 (pad 8)
    float* S  = (float*)(smem + 33280);        // [32][788] f32  (pad 4)
    float* rmax = (float*)(smem + 134144);     // [32]
    float* rinv = rmax + 32;                   // [32]
    int nb = blockIdx.x, b = blockIdx.y;
    int n0 = nb * 32;
    int t = threadIdx.x, w = t >> 6, l = t & 63;
    const u16* pb = proj + (size_t)b * NN * M3;
    {   // stage theta rows n0..n0+31 (reads into tail pad for the last block)
        int row = t >> 3, kb = (t & 7) * 64;
        const u16* src = pb + (size_t)(n0 + row) * M3 + kb;
        u16* dst = th + row * 520 + kb;
        #pragma unroll
        for (int q = 0; q < 8; ++q) *(s16x8*)(dst + q * 8) = *(const s16x8*)(src + q * 8);
    }
    __syncthreads();
    int lc = l & 15, lr = l >> 4, ko = lr * 8;
    for (int mtile = w; mtile < 49; mtile += 4) {
        f32x4 a0 = {0.f, 0.f, 0.f, 0.f}, a1 = {0.f, 0.f, 0.f, 0.f};
        const u16* ph = pb + 512 + (size_t)(mtile * 16 + lc) * M3;  // phi^T row m
        #pragma unroll
        for (int ks = 0; ks < 16; ++ks) {
            s16x8 bfrag = *(const s16x8*)(ph + ks * 32 + ko);
            s16x8 t0 = *(const s16x8*)(th + lc * 520 + ks * 32 + ko);
            s16x8 t1 = *(const s16x8*)(th + (16 + lc) * 520 + ks * 32 + ko);
            a0 = __builtin_amdgcn_mfma_f32_16x16x32_bf16(t0, bfrag, a0, 0, 0, 0);
            a1 = __builtin_amdgcn_mfma_f32_16x16x32_bf16(t1, bfrag, a1, 0, 0, 0);
        }
        int m = mtile * 16 + lc;
        #pragma unroll
        for (int r = 0; r < 4; ++r) {
            S[(lr * 4 + r) * 788 + m]        = a0[r];
            S[(16 + lr * 4 + r) * 788 + m]   = a1[r];
        }
    }
    __syncthreads();
    for (int r = w; r < 32; r += 4) {
        const float* Sr = S + r * 788;
        float mx = -1e30f;
        for (int m = l; m < NN; m += 64) mx = fmaxf(mx, Sr[m]);
        #pragma unroll
        for (int o = 32; o; o >>= 1) mx = fmaxf(mx, __shfl_xor(mx, o));
        float sm = 0.f;
        for (int m = l; m < NN; m += 64) sm += __expf(Sr[m] - mx);
        sm = wred_sum(sm);
        if (l == 0) { rmax[r] = mx; rinv[r] = 1.f / sm; }
    }
    __syncthreads();
    int nvalid = NN - n0; if (nvalid > 32) nvalid = 32;
    for (int m = t; m < NN; m += 256) {
        float cs = 0.f;
        for (int r = 0; r < nvalid; ++r) cs += __expf(S[r * 788 + m] - rmax[r]) * rinv[r];
        atomicAdd(&abar[b * NN + m], cs);
    }
}

// ---- K3a: ybar[b][i] = sum_m abar[b][m] * g^T[b][m][i]  (i in [0,512)) ----
__global__ __launch_bounds__(256) void k_ybar(const u16* __restrict__ proj,
                                              const float* __restrict__ abar,
                                              float* __restrict__ ybar) {
    __shared__ float part[4][CI];
    __shared__ float ab[49];
    int b = blockIdx.y, m0 = blockIdx.x * 49;
    int t = threadIdx.x, r = t >> 6, l = t & 63;
    if (t < 49) ab[t] = abar[b * NN + m0 + t];
    __syncthreads();
    const u16* g = proj + (size_t)b * NN * M3 + 1024;
    float acc[8] = {};
    for (int m = m0 + r; m < m0 + 49; m += 4) {
        float a = ab[m - m0];
        s16x8 v = *(const s16x8*)(g + (size_t)m * M3 + l * 8);
        #pragma unroll
        for (int j = 0; j < 8; ++j) acc[j] += a * bf2f((u16)v[j]);
    }
    #pragma unroll
    for (int j = 0; j < 8; ++j) part[r][l * 8 + j] = acc[j];
    __syncthreads();
    if (r == 0) {
        #pragma unroll
        for (int j = 0; j < 8; ++j) {
            int i = l * 8 + j;
            atomicAdd(&ybar[b * CI + i],
                      part[0][i] + part[1][i] + part[2][i] + part[3][i]);
        }
    }
}

// ---- K3b: pooled[b][c] = inv*(Ww.ybar/784 + bw) + beta - mean*inv + xbar/784 ----
__global__ __launch_bounds__(256) void k_pooled(const float* __restrict__ ybar,
        const float* __restrict__ xbar,
        const float* __restrict__ Ww, const float* __restrict__ bw,
        const float* __restrict__ gamma, const float* __restrict__ beta,
        const float* __restrict__ mean, const float* __restrict__ var,
        float* __restrict__ pooled) {
    __shared__ float yb[CI];
    int b = blockIdx.y, c0 = blockIdx.x * 128;
    int t = threadIdx.x, w = t >> 6, l = t & 63;
    for (int i = t; i < CI; i += 256) yb[i] = ybar[b * CI + i] * (1.f / 784.f);
    __syncthreads();
    for (int c = c0 + w; c < c0 + 128; c += 4) {
        const float* wr = Ww + (size_t)c * CI;
        float s = 0.f;
        #pragma unroll
        for (int q = 0; q < 8; ++q) s += wr[q * 64 + l] * yb[q * 64 + l];
        s = wred_sum(s);
        if (l == 0) {
            float inv = gamma[c] * rsqrtf(var[c] + 1e-5f);
            pooled[b * NC + c] = inv * (s + bw[c]) + beta[c] - mean[c] * inv
                               + xbar[b * NC + c] * (1.f / 784.f);
        }
    }
}

// ---- K3c: h[b][j] = W1[j].pooled[b] + b1[j] ----
__global__ __launch_bounds__(256) void k_fc1(const float* __restrict__ pooled,
        const float* __restrict__ W1, const float* __restrict__ b1,
        float* __restrict__ h) {
    __shared__ float pb[NC];
    int b = blockIdx.y, j0 = blockIdx.x * 64;
    int t = threadIdx.x, w = t >> 6, l = t & 63;
    for (int i = t; i < NC; i += 256) pb[i] = pooled[b * NC + i];
    __syncthreads();
    for (int j = j0 + w; j < j0 + 64; j += 4) {
        const float* wr = W1 + (size_t)j * NC;
        float s = 0.f;
        #pragma unroll
        for (int q = 0; q < 16; ++q) s += wr[q * 64 + l] * pb[q * 64 + l];
        s = wred_sum(s);
        if (l == 0) h[b * CI + j] = s + b1[j];
    }
}

// ---- K3d: out[b][k] = W2[k].cat(h[b], x_face[b]) + b2[k] ----
__global__ __launch_bounds__(128) void k_fc2(const float* __restrict__ h,
        const float* __restrict__ x_face,
        const float* __restrict__ W2, const float* __restrict__ b2,
        float* __restrict__ out) {
    int b = blockIdx.x, t = threadIdx.x, w = t >> 6, l = t & 63;
    const float* wr = W2 + (size_t)w * NC;
    float s = 0.f;
    #pragma unroll
    for (int q = 0; q < 16; ++q) {
        int qq = q * 64 + l;
        float cv = (qq < 512) ? h[b * CI + qq] : x_face[(size_t)b * 512 + qq - 512];
        s += wr[qq] * cv;
    }
    s = wred_sum(s);
    if (l == 0) out[b * 2 + w] = s + b2[w];
}

extern "C" void kernel_launch(void* const* d_in, const int* in_sizes, int n_in,
                              void* d_out, int out_size, void* d_ws, size_t ws_size,
                              hipStream_t stream) {
    const float* x_body = (const float*)d_in[0];
    const float* x_face = (const float*)d_in[1];
    const float* Wg  = (const float*)d_in[2];
    const float* bg  = (const float*)d_in[3];
    const float* Wth = (const float*)d_in[4];
    const float* bth = (const float*)d_in[5];
    const float* Wph = (const float*)d_in[6];
    const float* bph = (const float*)d_in[7];
    const float* Ww  = (const float*)d_in[8];
    const float* bw  = (const float*)d_in[9];
    const float* gamma = (const float*)d_in[10];
    const float* beta  = (const float*)d_in[11];
    const float* mean  = (const float*)d_in[12];
    const float* var   = (const float*)d_in[13];
    const float* W1 = (const float*)d_in[14];
    const float* b1 = (const float*)d_in[15];
    const float* W2 = (const float*)d_in[16];
    const float* b2 = (const float*)d_in[17];
    (void)in_sizes; (void)n_in; (void)out_size; (void)ws_size;

    char* ws = (char*)d_ws;
    u16* xbT   = (u16*)(ws + OFF_XBT);
    u16* Wcat  = (u16*)(ws + OFF_WCAT);
    u16* proj  = (u16*)(ws + OFF_PROJ);
    float* abar = (float*)(ws + OFF_ABAR);
    float* xbar = (float*)(ws + OFF_XBAR);
    float* ybar = (float*)(ws + OFF_YBAR);   // reuses xbT region (dead after k_gemm)
    float* pooled = (float*)(ws + OFF_POOL);
    float* hbuf = (float*)(ws + OFF_H);

    // zero the atomic accumulators (abar + xbar are contiguous)
    hipMemsetAsync(ws + OFF_ABAR, 0, 100352 + 131072, stream);

    k_cast_w<<<1536, 256, 0, stream>>>(Wth, Wph, Wg, Wcat);
    k_tcast<<<dim3(25, 32, 32), 256, 0, stream>>>(x_body, xbT, xbar);
    k_gemm<<<dim3(7, 12, 32), 256, 0, stream>>>(xbT, Wcat, bth, bph, bg, proj);
    // xbT now dead; zero the ybar accumulator living in its space
    hipMemsetAsync(ws + OFF_YBAR, 0, 65536, stream);
    k_attn<<<dim3(25, 32), 256, 134400, stream>>>(proj, abar);
    k_ybar<<<dim3(16, 32), 256, 0, stream>>>(proj, abar, ybar);
    k_pooled<<<dim3(8, 32), 256, 0, stream>>>(ybar, xbar, Ww, bw,
                                              gamma, beta, mean, var, pooled);
    k_fc1<<<dim3(8, 32), 256, 0, stream>>>(pooled, W1, b1, hbuf);
    k_fc2<<<32, 128, 0, stream>>>(hbuf, x_face, W2, b2, (float*)d_out);
}

// Round 3
// 548.430 us; speedup vs baseline: 1.6648x; 1.1626x over previous
//
#include <hip/hip_runtime.h>

typedef unsigned short u16;
typedef float f32x4 __attribute__((ext_vector_type(4)));
typedef short s16x8 __attribute__((ext_vector_type(8)));

#define NB 32          // batch
#define NC 1024        // channels
#define CI 512         // inter channels
#define NN 784         // spatial positions
#define NPAD 896       // 7*128
#define M3 1536        // 3*CI

// ---- workspace layout (bytes) ----
#define OFF_XBT   0ull                      // bf16 [NB][NPAD][NC]        58,720,256
#define OFF_WCAT  58720256ull               // bf16 [1536][1024]           3,145,728
#define OFF_PROJ  61865984ull               // bf16 [NB][784][1536]+pad   77,119,488
#define OFF_ABAR  138985472ull              // f32  [NB][784]                100,352
#define OFF_XBAR  139085824ull              // f32  [NB][1024]               131,072
// reuse of the xbT region after k_gemm no longer needs it:
#define OFF_YBAR  0ull                      // f32 [NB][512]   65,536
#define OFF_POOL  65536ull                  // f32 [NB][1024] 131,072
#define OFF_H     196608ull                 // f32 [NB][512]   65,536

__device__ __forceinline__ u16 f2bf(float x) {
    union { float f; unsigned u; } v; v.f = x;
    unsigned r = v.u + 0x7fffu + ((v.u >> 16) & 1u);
    return (u16)(r >> 16);
}
__device__ __forceinline__ float bf2f(u16 h) {
    union { unsigned u; float f; } v; v.u = ((unsigned)h) << 16;
    return v.f;
}
__device__ __forceinline__ void gload16(const u16* g, u16* l) {
    __builtin_amdgcn_global_load_lds(
        (const __attribute__((address_space(1))) unsigned int*)(const void*)g,
        (__attribute__((address_space(3))) unsigned int*)(void*)l,
        16, 0, 0);
}
__device__ __forceinline__ float wred_sum(float s) {
    #pragma unroll
    for (int o = 32; o; o >>= 1) s += __shfl_xor(s, o);
    return s;
}

// ---- K0a: cast the three projection weights into one bf16 [1536][1024] ----
__global__ void k_cast_w(const float* __restrict__ Wth, const float* __restrict__ Wph,
                         const float* __restrict__ Wg, u16* __restrict__ Wcat) {
    int T = blockIdx.x * 256 + threadIdx.x;
    int e = T * 4;
    int row = e >> 10, col = e & 1023;
    const float* src = (row < 512) ? (Wth + (size_t)row * 1024)
                     : (row < 1024) ? (Wph + (size_t)(row - 512) * 1024)
                                    : (Wg + (size_t)(row - 1024) * 1024);
    float4 v = *(const float4*)(src + col);
    ushort4 o;
    o.x = f2bf(v.x); o.y = f2bf(v.y); o.z = f2bf(v.z); o.w = f2bf(v.w);
    *(ushort4*)(Wcat + e) = o;
}

// ---- K0b: transpose-cast x_body [b][c][n] f32 -> xbT [b][n][c] bf16, + xbar sums ----
__global__ void k_tcast(const float* __restrict__ xb, u16* __restrict__ xbT,
                        float* __restrict__ xbar) {
    __shared__ float tile[32][33];
    int b = blockIdx.z, c0 = blockIdx.y * 32, n0 = blockIdx.x * 32;
    int t = threadIdx.x, j = t & 31, r0 = t >> 5;
    const float* xp = xb + ((size_t)b * NC + c0) * NN;
    #pragma unroll
    for (int rr = r0; rr < 32; rr += 8) {
        int n = n0 + j;
        tile[rr][j] = (n < NN) ? xp[(size_t)rr * NN + n] : 0.f;
    }
    __syncthreads();
    if (t < 32) {
        float s = 0.f;
        #pragma unroll
        for (int q = 0; q < 32; ++q) s += tile[t][q];
        atomicAdd(&xbar[b * NC + c0 + t], s);
    }
    #pragma unroll
    for (int rr = r0; rr < 32; rr += 8) {
        int n = n0 + rr;
        if (n < NN) xbT[((size_t)b * NPAD + n)* NC + c0 + j] = f2bf(tile[j][rr]);
    }
}

// ---- K1: projections GEMM. OUT[b][n][m] = sum_k xbT[b][n][k]*Wcat[m][k] + bias[m]
// m 0..511 = theta, 512..1023 = phi^T, 1024..1535 = g^T. 128x128 tile, BK=32.
// 1D grid 2688 = 8 XCDs x (4 b x 12 mt x 7 nt): each XCD owns 4 whole batches
// so A-panels and Wcat stay L2-resident per XCD. ----
__global__ __launch_bounds__(256) void k_gemm(
        const u16* __restrict__ xbT, const u16* __restrict__ Wcat,
        const float* __restrict__ bth, const float* __restrict__ bph,
        const float* __restrict__ bg, u16* __restrict__ proj) {
    __shared__ u16 At[128 * 32];
    __shared__ u16 Bt[128 * 32];
    int orig = blockIdx.x;
    int xcd = orig & 7, slot = orig >> 3;          // 336 slots per XCD
    int b = xcd * 4 + slot / 84;
    int rem = slot % 84;
    int nt = rem / 12, mt = rem % 12;              // mt fastest: A-panel reused 12x
    int t = threadIdx.x, w = t >> 6, l = t & 63;
    int wn = w & 1, wm = w >> 1;
    const u16* Ag = xbT + (size_t)b * NPAD * NC + (size_t)nt * 128 * NC;
    const u16* Bg = Wcat + (size_t)mt * 128 * NC;
    int lrow = l >> 2;                       // row within 16-row segment
    int cg = ((l & 3) ^ ((l >> 3) & 3)) * 8; // pre-swizzled global k-chunk (elems)
    int lc = l & 15, lr = l >> 4;
    int sA = (lr ^ ((lc >> 1) & 3)) * 8;     // swizzled LDS read slot (elems)
    f32x4 acc[4][4] = {};
    for (int kt = 0; kt < 32; ++kt) {
        int k0 = kt * 32;
        int s0 = w * 2, s1 = w * 2 + 1;
        gload16(Ag + (size_t)(s0 * 16 + lrow) * NC + k0 + cg, At + s0 * 512);
        gload16(Ag + (size_t)(s1 * 16 + lrow) * NC + k0 + cg, At + s1 * 512);
        gload16(Bg + (size_t)(s0 * 16 + lrow) * NC + k0 + cg, Bt + s0 * 512);
        gload16(Bg + (size_t)(s1 * 16 + lrow) * NC + k0 + cg, Bt + s1 * 512);
        __syncthreads();   // drains vmcnt + barrier
        s16x8 af[4], bf_[4];
        #pragma unroll
        for (int i = 0; i < 4; ++i)
            af[i] = *(const s16x8*)&At[(wn * 64 + i * 16 + lc) * 32 + sA];
        #pragma unroll
        for (int jj = 0; jj < 4; ++jj)
            bf_[jj] = *(const s16x8*)&Bt[(wm * 64 + jj * 16 + lc) * 32 + sA];
        #pragma unroll
        for (int i = 0; i < 4; ++i)
            #pragma unroll
            for (int jj = 0; jj < 4; ++jj)
                acc[i][jj] = __builtin_amdgcn_mfma_f32_16x16x32_bf16(af[i], bf_[jj], acc[i][jj], 0, 0, 0);
        __syncthreads();
    }
    size_t ob = (size_t)b * NN * M3;
    #pragma unroll
    for (int jj = 0; jj < 4; ++jj) {
        int m = mt * 128 + wm * 64 + jj * 16 + lc;
        float bv = (m < 512) ? bth[m] : (m < 1024) ? bph[m - 512] : bg[m - 1024];
        #pragma unroll
        for (int i = 0; i < 4; ++i) {
            int nbase = nt * 128 + wn * 64 + i * 16 + lr * 4;
            #pragma unroll
            for (int r = 0; r < 4; ++r) {
                int n = nbase + r;
                if (n < NN) proj[ob + (size_t)n * M3 + m] = f2bf(acc[i][jj][r] + bv);
            }
        }
    }
}

// ---- K2: attention logits + softmax + column sums, S register-resident.
// Block = 32 theta-rows; wave w owns mtiles {w, w+4, ...} (<=13 tiles of 16 cols).
// 1D grid 800 = 8 XCDs x (4 b x 25 nb): phi L2-resident per XCD. ----
__global__ __launch_bounds__(256) void k_attn(const u16* __restrict__ proj,
                                              float* __restrict__ abar) {
    __shared__ u16 th[32 * 520];     // theta tile, +8 pad per row
    __shared__ float wmax[4][32];
    __shared__ float wsum[4][32];
    int orig = blockIdx.x;
    int xcd = orig & 7, slot = orig >> 3;          // 100 slots per XCD
    int b = xcd * 4 + slot / 25;
    int nb = slot % 25;
    int n0 = nb * 32;
    int t = threadIdx.x, w = t >> 6, l = t & 63;
    const u16* pb = proj + (size_t)b * NN * M3;
    {   // stage theta rows n0..n0+31 (tail block reads pad rows; content ~0, harmless)
        int row = t >> 3, kb = (t & 7) * 64;
        const u16* src = pb + (size_t)(n0 + row) * M3 + kb;
        u16* dst = th + row * 520 + kb;
        #pragma unroll
        for (int q = 0; q < 8; ++q) *(s16x8*)(dst + q * 8) = *(const s16x8*)(src + q * 8);
    }
    __syncthreads();
    int lc = l & 15, lr = l >> 4, ko = lr * 8;
    // ---- compute S tiles into registers ----
    f32x4 a0[13], a1[13];
    #pragma unroll
    for (int it = 0; it < 13; ++it) {
        a0[it] = (f32x4){0.f, 0.f, 0.f, 0.f};
        a1[it] = (f32x4){0.f, 0.f, 0.f, 0.f};
    }
    #pragma unroll
    for (int it = 0; it < 13; ++it) {
        int mtile = w + it * 4;
        if (mtile < 49) {
            const u16* ph = pb + 512 + (size_t)(mtile * 16 + lc) * M3 + ko;
            #pragma unroll
            for (int ks = 0; ks < 16; ++ks) {
                s16x8 bfrag = *(const s16x8*)(ph + ks * 32);
                s16x8 t0 = *(const s16x8*)(th + lc * 520 + ks * 32 + ko);
                s16x8 t1 = *(const s16x8*)(th + (16 + lc) * 520 + ks * 32 + ko);
                a0[it] = __builtin_amdgcn_mfma_f32_16x16x32_bf16(t0, bfrag, a0[it], 0, 0, 0);
                a1[it] = __builtin_amdgcn_mfma_f32_16x16x32_bf16(t1, bfrag, a1[it], 0, 0, 0);
            }
        }
    }
    // lane's rows: a0 -> lr*4+j ; a1 -> 16+lr*4+j   (j=0..3)
    // ---- row max over this wave's m-subset ----
    float pm0[4], pm1[4];
    #pragma unroll
    for (int j = 0; j < 4; ++j) { pm0[j] = -1e30f; pm1[j] = -1e30f; }
    #pragma unroll
    for (int it = 0; it < 13; ++it) {
        if (w + it * 4 < 49) {
            #pragma unroll
            for (int j = 0; j < 4; ++j) {
                pm0[j] = fmaxf(pm0[j], a0[it][j]);
                pm1[j] = fmaxf(pm1[j], a1[it][j]);
            }
        }
    }
    #pragma unroll
    for (int o = 1; o < 16; o <<= 1) {
        #pragma unroll
        for (int j = 0; j < 4; ++j) {
            pm0[j] = fmaxf(pm0[j], __shfl_xor(pm0[j], o));
            pm1[j] = fmaxf(pm1[j], __shfl_xor(pm1[j], o));
        }
    }
    if (lc == 0) {
        #pragma unroll
        for (int j = 0; j < 4; ++j) {
            wmax[w][lr * 4 + j] = pm0[j];
            wmax[w][16 + lr * 4 + j] = pm1[j];
        }
    }
    __syncthreads();
    float mx0[4], mx1[4];
    #pragma unroll
    for (int j = 0; j < 4; ++j) {
        mx0[j] = fmaxf(fmaxf(wmax[0][lr * 4 + j], wmax[1][lr * 4 + j]),
                       fmaxf(wmax[2][lr * 4 + j], wmax[3][lr * 4 + j]));
        mx1[j] = fmaxf(fmaxf(wmax[0][16 + lr * 4 + j], wmax[1][16 + lr * 4 + j]),
                       fmaxf(wmax[2][16 + lr * 4 + j], wmax[3][16 + lr * 4 + j]));
    }
    // ---- exp in place + row sums ----
    float ps0[4] = {}, ps1[4] = {};
    #pragma unroll
    for (int it = 0; it < 13; ++it) {
        if (w + it * 4 < 49) {
            #pragma unroll
            for (int j = 0; j < 4; ++j) {
                float e0 = __expf(a0[it][j] - mx0[j]);
                float e1 = __expf(a1[it][j] - mx1[j]);
                a0[it][j] = e0; ps0[j] += e0;
                a1[it][j] = e1; ps1[j] += e1;
            }
        }
    }
    #pragma unroll
    for (int o = 1; o < 16; o <<= 1) {
        #pragma unroll
        for (int j = 0; j < 4; ++j) {
            ps0[j] += __shfl_xor(ps0[j], o);
            ps1[j] += __shfl_xor(ps1[j], o);
        }
    }
    if (lc == 0) {
        #pragma unroll
        for (int j = 0; j < 4; ++j) {
            wsum[w][lr * 4 + j] = ps0[j];
            wsum[w][16 + lr * 4 + j] = ps1[j];
        }
    }
    __syncthreads();
    float ri0[4], ri1[4];
    #pragma unroll
    for (int j = 0; j < 4; ++j) {
        float s0 = wsum[0][lr * 4 + j] + wsum[1][lr * 4 + j]
                 + wsum[2][lr * 4 + j] + wsum[3][lr * 4 + j];
        float s1 = wsum[0][16 + lr * 4 + j] + wsum[1][16 + lr * 4 + j]
                 + wsum[2][16 + lr * 4 + j] + wsum[3][16 + lr * 4 + j];
        ri0[j] = (n0 + lr * 4 + j < NN) ? 1.f / s0 : 0.f;       // mask pad rows
        ri1[j] = (n0 + 16 + lr * 4 + j < NN) ? 1.f / s1 : 0.f;
    }
    // ---- column sums -> abar ----
    #pragma unroll
    for (int it = 0; it < 13; ++it) {
        int mtile = w + it * 4;
        if (mtile < 49) {
            float cs = 0.f;
            #pragma unroll
            for (int j = 0; j < 4; ++j)
                cs += a0[it][j] * ri0[j] + a1[it][j] * ri1[j];
            cs += __shfl_xor(cs, 16);
            cs += __shfl_xor(cs, 32);
            if (lr == 0)
                atomicAdd(&abar[b * NN + mtile * 16 + lc], cs);
        }
    }
}

// ---- K3a: ybar[b][i] = sum_m abar[b][m] * g^T[b][m][i]  (i in [0,512)) ----
__global__ __launch_bounds__(256) void k_ybar(const u16* __restrict__ proj,
                                              const float* __restrict__ abar,
                                              float* __restrict__ ybar) {
    __shared__ float part[4][CI];
    __shared__ float ab[49];
    int b = blockIdx.y, m0 = blockIdx.x * 49;
    int t = threadIdx.x, r = t >> 6, l = t & 63;
    if (t < 49) ab[t] = abar[b * NN + m0 + t];
    __syncthreads();
    const u16* g = proj + (size_t)b * NN * M3 + 1024;
    float acc[8] = {};
    for (int m = m0 + r; m < m0 + 49; m += 4) {
        float a = ab[m - m0];
        s16x8 v = *(const s16x8*)(g + (size_t)m * M3 + l * 8);
        #pragma unroll
        for (int j = 0; j < 8; ++j) acc[j] += a * bf2f((u16)v[j]);
    }
    #pragma unroll
    for (int j = 0; j < 8; ++j) part[r][l * 8 + j] = acc[j];
    __syncthreads();
    if (r == 0) {
        #pragma unroll
        for (int j = 0; j < 8; ++j) {
            int i = l * 8 + j;
            atomicAdd(&ybar[b * CI + i],
                      part[0][i] + part[1][i] + part[2][i] + part[3][i]);
        }
    }
}

// ---- K3b: pooled[b][c] = inv*(Ww.ybar/784 + bw) + beta - mean*inv + xbar/784 ----
__global__ __launch_bounds__(256) void k_pooled(const float* __restrict__ ybar,
        const float* __restrict__ xbar,
        const float* __restrict__ Ww, const float* __restrict__ bw,
        const float* __restrict__ gamma, const float* __restrict__ beta,
        const float* __restrict__ mean, const float* __restrict__ var,
        float* __restrict__ pooled) {
    __shared__ float yb[CI];
    int b = blockIdx.y, c0 = blockIdx.x * 128;
    int t = threadIdx.x, w = t >> 6, l = t & 63;
    for (int i = t; i < CI; i += 256) yb[i] = ybar[b * CI + i] * (1.f / 784.f);
    __syncthreads();
    for (int c = c0 + w; c < c0 + 128; c += 4) {
        const float* wr = Ww + (size_t)c * CI;
        float s = 0.f;
        #pragma unroll
        for (int q = 0; q < 8; ++q) s += wr[q * 64 + l] * yb[q * 64 + l];
        s = wred_sum(s);
        if (l == 0) {
            float inv = gamma[c] * rsqrtf(var[c] + 1e-5f);
            pooled[b * NC + c] = inv * (s + bw[c]) + beta[c] - mean[c] * inv
                               + xbar[b * NC + c] * (1.f / 784.f);
        }
    }
}

// ---- K3c: h[b][j] = W1[j].pooled[b] + b1[j] ----
__global__ __launch_bounds__(256) void k_fc1(const float* __restrict__ pooled,
        const float* __restrict__ W1, const float* __restrict__ b1,
        float* __restrict__ h) {
    __shared__ float pb[NC];
    int b = blockIdx.y, j0 = blockIdx.x * 64;
    int t = threadIdx.x, w = t >> 6, l = t & 63;
    for (int i = t; i < NC; i += 256) pb[i] = pooled[b * NC + i];
    __syncthreads();
    for (int j = j0 + w; j < j0 + 64; j += 4) {
        const float* wr = W1 + (size_t)j * NC;
        float s = 0.f;
        #pragma unroll
        for (int q = 0; q < 16; ++q) s += wr[q * 64 + l] * pb[q * 64 + l];
        s = wred_sum(s);
        if (l == 0) h[b * CI + j] = s + b1[j];
    }
}

// ---- K3d: out[b][k] = W2[k].cat(h[b], x_face[b]) + b2[k] ----
__global__ __launch_bounds__(128) void k_fc2(const float* __restrict__ h,
        const float* __restrict__ x_face,
        const float* __restrict__ W2, const float* __restrict__ b2,
        float* __restrict__ out) {
    int b = blockIdx.x, t = threadIdx.x, w = t >> 6, l = t & 63;
    const float* wr = W2 + (size_t)w * NC;
    float s = 0.f;
    #pragma unroll
    for (int q = 0; q < 16; ++q) {
        int qq = q * 64 + l;
        float cv = (qq < 512) ? h[b * CI + qq] : x_face[(size_t)b * 512 + qq - 512];
        s += wr[qq] * cv;
    }
    s = wred_sum(s);
    if (l == 0) out[b * 2 + w] = s + b2[w];
}

extern "C" void kernel_launch(void* const* d_in, const int* in_sizes, int n_in,
                              void* d_out, int out_size, void* d_ws, size_t ws_size,
                              hipStream_t stream) {
    const float* x_body = (const float*)d_in[0];
    const float* x_face = (const float*)d_in[1];
    const float* Wg  = (const float*)d_in[2];
    const float* bg  = (const float*)d_in[3];
    const float* Wth = (const float*)d_in[4];
    const float* bth = (const float*)d_in[5];
    const float* Wph = (const float*)d_in[6];
    const float* bph = (const float*)d_in[7];
    const float* Ww  = (const float*)d_in[8];
    const float* bw  = (const float*)d_in[9];
    const float* gamma = (const float*)d_in[10];
    const float* beta  = (const float*)d_in[11];
    const float* mean  = (const float*)d_in[12];
    const float* var   = (const float*)d_in[13];
    const float* W1 = (const float*)d_in[14];
    const float* b1 = (const float*)d_in[15];
    const float* W2 = (const float*)d_in[16];
    const float* b2 = (const float*)d_in[17];
    (void)in_sizes; (void)n_in; (void)out_size; (void)ws_size;

    char* ws = (char*)d_ws;
    u16* xbT   = (u16*)(ws + OFF_XBT);
    u16* Wcat  = (u16*)(ws + OFF_WCAT);
    u16* proj  = (u16*)(ws + OFF_PROJ);
    float* abar = (float*)(ws + OFF_ABAR);
    float* xbar = (float*)(ws + OFF_XBAR);
    float* ybar = (float*)(ws + OFF_YBAR);   // reuses xbT region (dead after k_gemm)
    float* pooled = (float*)(ws + OFF_POOL);
    float* hbuf = (float*)(ws + OFF_H);

    // zero the atomic accumulators (abar + xbar are contiguous)
    hipMemsetAsync(ws + OFF_ABAR, 0, 100352 + 131072, stream);

    k_cast_w<<<1536, 256, 0, stream>>>(Wth, Wph, Wg, Wcat);
    k_tcast<<<dim3(25, 32, 32), 256, 0, stream>>>(x_body, xbT, xbar);
    k_gemm<<<2688, 256, 0, stream>>>(xbT, Wcat, bth, bph, bg, proj);
    // xbT now dead; zero the ybar accumulator living in its space
    hipMemsetAsync(ws + OFF_YBAR, 0, 65536, stream);
    k_attn<<<800, 256, 0, stream>>>(proj, abar);
    k_ybar<<<dim3(16, 32), 256, 0, stream>>>(proj, abar, ybar);
    k_pooled<<<dim3(8, 32), 256, 0, stream>>>(ybar, xbar, Ww, bw,
                                              gamma, beta, mean, var, pooled);
    k_fc1<<<dim3(8, 32), 256, 0, stream>>>(pooled, W1, b1, hbuf);
    k_fc2<<<32, 128, 0, stream>>>(hbuf, x_face, W2, b2, (float*)d_out);
}

// Round 4
// 534.557 us; speedup vs baseline: 1.7080x; 1.0260x over previous
//
#include <hip/hip_runtime.h>

typedef unsigned short u16;
typedef float f32x4 __attribute__((ext_vector_type(4)));
typedef short s16x8 __attribute__((ext_vector_type(8)));

#define NB 32          // batch
#define NC 1024        // channels
#define CI 512         // inter channels
#define NN 784         // spatial positions
#define NPAD 896       // 7*128
#define M3 1536        // 3*CI

// ---- workspace layout (bytes) ----
#define OFF_XBT   0ull                      // bf16 [NB][NPAD][NC]        58,720,256
#define OFF_WCAT  58720256ull               // bf16 [1536][1024]           3,145,728
#define OFF_PROJ  61865984ull               // bf16 [NB][784][1536]+pad   77,119,488
#define OFF_ABAR  138985472ull              // f32  [NB][784]                100,352
#define OFF_XBAR  139085824ull              // f32  [NB][1024]               131,072
// reuse of the xbT region after k_gemm no longer needs it:
#define OFF_YBAR  0ull                      // f32 [NB][512]   65,536
#define OFF_POOL  65536ull                  // f32 [NB][1024] 131,072
#define OFF_H     196608ull                 // f32 [NB][512]   65,536

__device__ __forceinline__ u16 f2bf(float x) {
    union { float f; unsigned u; } v; v.f = x;
    unsigned r = v.u + 0x7fffu + ((v.u >> 16) & 1u);
    return (u16)(r >> 16);
}
__device__ __forceinline__ float bf2f(u16 h) {
    union { unsigned u; float f; } v; v.u = ((unsigned)h) << 16;
    return v.f;
}
__device__ __forceinline__ void gload16(const u16* g, u16* l) {
    __builtin_amdgcn_global_load_lds(
        (const __attribute__((address_space(1))) unsigned int*)(const void*)g,
        (__attribute__((address_space(3))) unsigned int*)(void*)l,
        16, 0, 0);
}
__device__ __forceinline__ float wred_sum(float s) {
    #pragma unroll
    for (int o = 32; o; o >>= 1) s += __shfl_xor(s, o);
    return s;
}

// ---- K0a: cast the three projection weights into one bf16 [1536][1024] ----
__global__ void k_cast_w(const float* __restrict__ Wth, const float* __restrict__ Wph,
                         const float* __restrict__ Wg, u16* __restrict__ Wcat) {
    int T = blockIdx.x * 256 + threadIdx.x;
    int e = T * 4;
    int row = e >> 10, col = e & 1023;
    const float* src = (row < 512) ? (Wth + (size_t)row * 1024)
                     : (row < 1024) ? (Wph + (size_t)(row - 512) * 1024)
                                    : (Wg + (size_t)(row - 1024) * 1024);
    float4 v = *(const float4*)(src + col);
    ushort4 o;
    o.x = f2bf(v.x); o.y = f2bf(v.y); o.z = f2bf(v.z); o.w = f2bf(v.w);
    *(ushort4*)(Wcat + e) = o;
}

// ---- K0b: transpose-cast x_body [b][c][n] f32 -> xbT [b][n][c] bf16, + xbar sums ----
__global__ void k_tcast(const float* __restrict__ xb, u16* __restrict__ xbT,
                        float* __restrict__ xbar) {
    __shared__ float tile[32][33];
    int b = blockIdx.z, c0 = blockIdx.y * 32, n0 = blockIdx.x * 32;
    int t = threadIdx.x, j = t & 31, r0 = t >> 5;
    const float* xp = xb + ((size_t)b * NC + c0) * NN;
    #pragma unroll
    for (int rr = r0; rr < 32; rr += 8) {
        int n = n0 + j;
        tile[rr][j] = (n < NN) ? xp[(size_t)rr * NN + n] : 0.f;
    }
    __syncthreads();
    if (t < 32) {
        float s = 0.f;
        #pragma unroll
        for (int q = 0; q < 32; ++q) s += tile[t][q];
        atomicAdd(&xbar[b * NC + c0 + t], s);
    }
    #pragma unroll
    for (int rr = r0; rr < 32; rr += 8) {
        int n = n0 + rr;
        if (n < NN) xbT[((size_t)b * NPAD + n)* NC + c0 + j] = f2bf(tile[j][rr]);
    }
}

// ---- K1: projections GEMM. OUT[b][n][m] = sum_k xbT[b][n][k]*Wcat[m][k] + bias[m]
// m 0..511 = theta, 512..1023 = phi^T, 1024..1535 = g^T. 128x128 tile, BK=32.
// Double-buffered LDS: stage(kt+1) issued before compute(kt), one barrier/tile.
// Swapped-operand MFMA so each lane owns 4 consecutive m -> 8B packed stores.
// 1D grid 2688 = 8 XCDs x (4 b x 7 nt x 12 mt). ----
__global__ __launch_bounds__(256) void k_gemm(
        const u16* __restrict__ xbT, const u16* __restrict__ Wcat,
        const float* __restrict__ bth, const float* __restrict__ bph,
        const float* __restrict__ bg, u16* __restrict__ proj) {
    __shared__ u16 smem[2][8192];          // [sel][A 4096 | B 4096]
    int orig = blockIdx.x;
    int xcd = orig & 7, slot = orig >> 3;          // 336 slots per XCD
    int b = xcd * 4 + slot / 84;
    int rem = slot % 84;
    int nt = rem / 12, mt = rem % 12;              // mt fastest: A-panel reused 12x
    int t = threadIdx.x, w = t >> 6, l = t & 63;
    int wn = w & 1, wm = w >> 1;
    const u16* Ag = xbT + (size_t)b * NPAD * NC + (size_t)nt * 128 * NC;
    const u16* Bg = Wcat + (size_t)mt * 128 * NC;
    int lrow = l >> 2;                       // row within 16-row segment
    int cg = ((l & 3) ^ ((l >> 3) & 3)) * 8; // pre-swizzled global k-chunk (elems)
    int lc = l & 15, lr = l >> 4;
    int sA = (lr ^ ((lc >> 1) & 3)) * 8;     // swizzled LDS read slot (elems)
    const int s0 = w * 2, s1 = w * 2 + 1;

    f32x4 acc[4][4] = {};
    // prologue: stage tile 0
    {
        u16* A_ = smem[0]; u16* B_ = smem[0] + 4096;
        gload16(Ag + (size_t)(s0 * 16 + lrow) * NC + 0 + cg, A_ + s0 * 512);
        gload16(Ag + (size_t)(s1 * 16 + lrow) * NC + 0 + cg, A_ + s1 * 512);
        gload16(Bg + (size_t)(s0 * 16 + lrow) * NC + 0 + cg, B_ + s0 * 512);
        gload16(Bg + (size_t)(s1 * 16 + lrow) * NC + 0 + cg, B_ + s1 * 512);
    }
    __syncthreads();
    int cur = 0;
    for (int kt = 0; kt < 32; ++kt) {
        if (kt < 31) {   // stage next tile; lands before this iter's closing barrier
            int k0 = (kt + 1) * 32;
            u16* A_ = smem[cur ^ 1]; u16* B_ = smem[cur ^ 1] + 4096;
            gload16(Ag + (size_t)(s0 * 16 + lrow) * NC + k0 + cg, A_ + s0 * 512);
            gload16(Ag + (size_t)(s1 * 16 + lrow) * NC + k0 + cg, A_ + s1 * 512);
            gload16(Bg + (size_t)(s0 * 16 + lrow) * NC + k0 + cg, B_ + s0 * 512);
            gload16(Bg + (size_t)(s1 * 16 + lrow) * NC + k0 + cg, B_ + s1 * 512);
        }
        const u16* A_ = smem[cur]; const u16* B_ = smem[cur] + 4096;
        s16x8 af[4], bf_[4];
        #pragma unroll
        for (int i = 0; i < 4; ++i)
            af[i] = *(const s16x8*)&A_[(wn * 64 + i * 16 + lc) * 32 + sA];
        #pragma unroll
        for (int jj = 0; jj < 4; ++jj)
            bf_[jj] = *(const s16x8*)&B_[(wm * 64 + jj * 16 + lc) * 32 + sA];
        #pragma unroll
        for (int i = 0; i < 4; ++i)
            #pragma unroll
            for (int jj = 0; jj < 4; ++jj)   // swapped: rows->m, cols->n
                acc[i][jj] = __builtin_amdgcn_mfma_f32_16x16x32_bf16(bf_[jj], af[i], acc[i][jj], 0, 0, 0);
        __syncthreads();   // drains vmcnt (next tile landed) + lgkm
        cur ^= 1;
    }
    // epilogue: lane owns rows n = nt*128+wn*64+i*16+lc ; m = mt*128+wm*64+jj*16+lr*4+r
    const float* bias = (mt < 4) ? (bth + mt * 128)
                      : (mt < 8) ? (bph + (mt - 4) * 128)
                                 : (bg + (mt - 8) * 128);
    float4 bias4[4];
    #pragma unroll
    for (int jj = 0; jj < 4; ++jj)
        bias4[jj] = *(const float4*)(bias + wm * 64 + jj * 16 + lr * 4);
    size_t ob = (size_t)b * NN * M3;
    #pragma unroll
    for (int i = 0; i < 4; ++i) {
        int n = nt * 128 + wn * 64 + i * 16 + lc;
        if (n < NN) {
            #pragma unroll
            for (int jj = 0; jj < 4; ++jj) {
                int m = mt * 128 + wm * 64 + jj * 16 + lr * 4;
                ushort4 o;
                o.x = f2bf(acc[i][jj][0] + bias4[jj].x);
                o.y = f2bf(acc[i][jj][1] + bias4[jj].y);
                o.z = f2bf(acc[i][jj][2] + bias4[jj].z);
                o.w = f2bf(acc[i][jj][3] + bias4[jj].w);
                *(ushort4*)(proj + ob + (size_t)n * M3 + m) = o;
            }
        }
    }
}

// ---- K2: attention logits + softmax + column sums, S register-resident.
// Block = 32 theta-rows; wave w owns mtiles {w, w+4, ...} (<=13 tiles of 16 cols).
// 1D grid 800 = 8 XCDs x (4 b x 25 nb): phi L2-resident per XCD. ----
__global__ __launch_bounds__(256) void k_attn(const u16* __restrict__ proj,
                                              float* __restrict__ abar) {
    __shared__ u16 th[32 * 520];     // theta tile, +8 pad per row
    __shared__ float wmax[4][32];
    __shared__ float wsum[4][32];
    int orig = blockIdx.x;
    int xcd = orig & 7, slot = orig >> 3;          // 100 slots per XCD
    int b = xcd * 4 + slot / 25;
    int nb = slot % 25;
    int n0 = nb * 32;
    int t = threadIdx.x, w = t >> 6, l = t & 63;
    const u16* pb = proj + (size_t)b * NN * M3;
    {   // stage theta rows n0..n0+31 (tail block reads pad rows; content ~0, harmless)
        int row = t >> 3, kb = (t & 7) * 64;
        const u16* src = pb + (size_t)(n0 + row) * M3 + kb;
        u16* dst = th + row * 520 + kb;
        #pragma unroll
        for (int q = 0; q < 8; ++q) *(s16x8*)(dst + q * 8) = *(const s16x8*)(src + q * 8);
    }
    __syncthreads();
    int lc = l & 15, lr = l >> 4, ko = lr * 8;
    // ---- compute S tiles into registers ----
    f32x4 a0[13], a1[13];
    #pragma unroll
    for (int it = 0; it < 13; ++it) {
        a0[it] = (f32x4){0.f, 0.f, 0.f, 0.f};
        a1[it] = (f32x4){0.f, 0.f, 0.f, 0.f};
    }
    #pragma unroll
    for (int it = 0; it < 13; ++it) {
        int mtile = w + it * 4;
        if (mtile < 49) {
            const u16* ph = pb + 512 + (size_t)(mtile * 16 + lc) * M3 + ko;
            #pragma unroll
            for (int ks = 0; ks < 16; ++ks) {
                s16x8 bfrag = *(const s16x8*)(ph + ks * 32);
                s16x8 t0 = *(const s16x8*)(th + lc * 520 + ks * 32 + ko);
                s16x8 t1 = *(const s16x8*)(th + (16 + lc) * 520 + ks * 32 + ko);
                a0[it] = __builtin_amdgcn_mfma_f32_16x16x32_bf16(t0, bfrag, a0[it], 0, 0, 0);
                a1[it] = __builtin_amdgcn_mfma_f32_16x16x32_bf16(t1, bfrag, a1[it], 0, 0, 0);
            }
        }
    }
    // lane's rows: a0 -> lr*4+j ; a1 -> 16+lr*4+j   (j=0..3)
    // ---- row max over this wave's m-subset ----
    float pm0[4], pm1[4];
    #pragma unroll
    for (int j = 0; j < 4; ++j) { pm0[j] = -1e30f; pm1[j] = -1e30f; }
    #pragma unroll
    for (int it = 0; it < 13; ++it) {
        if (w + it * 4 < 49) {
            #pragma unroll
            for (int j = 0; j < 4; ++j) {
                pm0[j] = fmaxf(pm0[j], a0[it][j]);
                pm1[j] = fmaxf(pm1[j], a1[it][j]);
            }
        }
    }
    #pragma unroll
    for (int o = 1; o < 16; o <<= 1) {
        #pragma unroll
        for (int j = 0; j < 4; ++j) {
            pm0[j] = fmaxf(pm0[j], __shfl_xor(pm0[j], o));
            pm1[j] = fmaxf(pm1[j], __shfl_xor(pm1[j], o));
        }
    }
    if (lc == 0) {
        #pragma unroll
        for (int j = 0; j < 4; ++j) {
            wmax[w][lr * 4 + j] = pm0[j];
            wmax[w][16 + lr * 4 + j] = pm1[j];
        }
    }
    __syncthreads();
    float mx0[4], mx1[4];
    #pragma unroll
    for (int j = 0; j < 4; ++j) {
        mx0[j] = fmaxf(fmaxf(wmax[0][lr * 4 + j], wmax[1][lr * 4 + j]),
                       fmaxf(wmax[2][lr * 4 + j], wmax[3][lr * 4 + j]));
        mx1[j] = fmaxf(fmaxf(wmax[0][16 + lr * 4 + j], wmax[1][16 + lr * 4 + j]),
                       fmaxf(wmax[2][16 + lr * 4 + j], wmax[3][16 + lr * 4 + j]));
    }
    // ---- exp in place + row sums ----
    float ps0[4] = {}, ps1[4] = {};
    #pragma unroll
    for (int it = 0; it < 13; ++it) {
        if (w + it * 4 < 49) {
            #pragma unroll
            for (int j = 0; j < 4; ++j) {
                float e0 = __expf(a0[it][j] - mx0[j]);
                float e1 = __expf(a1[it][j] - mx1[j]);
                a0[it][j] = e0; ps0[j] += e0;
                a1[it][j] = e1; ps1[j] += e1;
            }
        }
    }
    #pragma unroll
    for (int o = 1; o < 16; o <<= 1) {
        #pragma unroll
        for (int j = 0; j < 4; ++j) {
            ps0[j] += __shfl_xor(ps0[j], o);
            ps1[j] += __shfl_xor(ps1[j], o);
        }
    }
    if (lc == 0) {
        #pragma unroll
        for (int j = 0; j < 4; ++j) {
            wsum[w][lr * 4 + j] = ps0[j];
            wsum[w][16 + lr * 4 + j] = ps1[j];
        }
    }
    __syncthreads();
    float ri0[4], ri1[4];
    #pragma unroll
    for (int j = 0; j < 4; ++j) {
        float s0 = wsum[0][lr * 4 + j] + wsum[1][lr * 4 + j]
                 + wsum[2][lr * 4 + j] + wsum[3][lr * 4 + j];
        float s1 = wsum[0][16 + lr * 4 + j] + wsum[1][16 + lr * 4 + j]
                 + wsum[2][16 + lr * 4 + j] + wsum[3][16 + lr * 4 + j];
        ri0[j] = (n0 + lr * 4 + j < NN) ? 1.f / s0 : 0.f;       // mask pad rows
        ri1[j] = (n0 + 16 + lr * 4 + j < NN) ? 1.f / s1 : 0.f;
    }
    // ---- column sums -> abar ----
    #pragma unroll
    for (int it = 0; it < 13; ++it) {
        int mtile = w + it * 4;
        if (mtile < 49) {
            float cs = 0.f;
            #pragma unroll
            for (int j = 0; j < 4; ++j)
                cs += a0[it][j] * ri0[j] + a1[it][j] * ri1[j];
            cs += __shfl_xor(cs, 16);
            cs += __shfl_xor(cs, 32);
            if (lr == 0)
                atomicAdd(&abar[b * NN + mtile * 16 + lc], cs);
        }
    }
}

// ---- K3a: ybar[b][i] = sum_m abar[b][m] * g^T[b][m][i]  (i in [0,512)) ----
__global__ __launch_bounds__(256) void k_ybar(const u16* __restrict__ proj,
                                              const float* __restrict__ abar,
                                              float* __restrict__ ybar) {
    __shared__ float part[4][CI];
    __shared__ float ab[49];
    int b = blockIdx.y, m0 = blockIdx.x * 49;
    int t = threadIdx.x, r = t >> 6, l = t & 63;
    if (t < 49) ab[t] = abar[b * NN + m0 + t];
    __syncthreads();
    const u16* g = proj + (size_t)b * NN * M3 + 1024;
    float acc[8] = {};
    for (int m = m0 + r; m < m0 + 49; m += 4) {
        float a = ab[m - m0];
        s16x8 v = *(const s16x8*)(g + (size_t)m * M3 + l * 8);
        #pragma unroll
        for (int j = 0; j < 8; ++j) acc[j] += a * bf2f((u16)v[j]);
    }
    #pragma unroll
    for (int j = 0; j < 8; ++j) part[r][l * 8 + j] = acc[j];
    __syncthreads();
    if (r == 0) {
        #pragma unroll
        for (int j = 0; j < 8; ++j) {
            int i = l * 8 + j;
            atomicAdd(&ybar[b * CI + i],
                      part[0][i] + part[1][i] + part[2][i] + part[3][i]);
        }
    }
}

// ---- K3b: pooled[b][c] = inv*(Ww.ybar/784 + bw) + beta - mean*inv + xbar/784 ----
__global__ __launch_bounds__(256) void k_pooled(const float* __restrict__ ybar,
        const float* __restrict__ xbar,
        const float* __restrict__ Ww, const float* __restrict__ bw,
        const float* __restrict__ gamma, const float* __restrict__ beta,
        const float* __restrict__ mean, const float* __restrict__ var,
        float* __restrict__ pooled) {
    __shared__ float yb[CI];
    int b = blockIdx.y, c0 = blockIdx.x * 128;
    int t = threadIdx.x, w = t >> 6, l = t & 63;
    for (int i = t; i < CI; i += 256) yb[i] = ybar[b * CI + i] * (1.f / 784.f);
    __syncthreads();
    for (int c = c0 + w; c < c0 + 128; c += 4) {
        const float* wr = Ww + (size_t)c * CI;
        float s = 0.f;
        #pragma unroll
        for (int q = 0; q < 8; ++q) s += wr[q * 64 + l] * yb[q * 64 + l];
        s = wred_sum(s);
        if (l == 0) {
            float inv = gamma[c] * rsqrtf(var[c] + 1e-5f);
            pooled[b * NC + c] = inv * (s + bw[c]) + beta[c] - mean[c] * inv
                               + xbar[b * NC + c] * (1.f / 784.f);
        }
    }
}

// ---- K3c: h[b][j] = W1[j].pooled[b] + b1[j] ----
__global__ __launch_bounds__(256) void k_fc1(const float* __restrict__ pooled,
        const float* __restrict__ W1, const float* __restrict__ b1,
        float* __restrict__ h) {
    __shared__ float pb[NC];
    int b = blockIdx.y, j0 = blockIdx.x * 64;
    int t = threadIdx.x, w = t >> 6, l = t & 63;
    for (int i = t; i < NC; i += 256) pb[i] = pooled[b * NC + i];
    __syncthreads();
    for (int j = j0 + w; j < j0 + 64; j += 4) {
        const float* wr = W1 + (size_t)j * NC;
        float s = 0.f;
        #pragma unroll
        for (int q = 0; q < 16; ++q) s += wr[q * 64 + l] * pb[q * 64 + l];
        s = wred_sum(s);
        if (l == 0) h[b * CI + j] = s + b1[j];
    }
}

// ---- K3d: out[b][k] = W2[k].cat(h[b], x_face[b]) + b2[k] ----
__global__ __launch_bounds__(128) void k_fc2(const float* __restrict__ h,
        const float* __restrict__ x_face,
        const float* __restrict__ W2, const float* __restrict__ b2,
        float* __restrict__ out) {
    int b = blockIdx.x, t = threadIdx.x, w = t >> 6, l = t & 63;
    const float* wr = W2 + (size_t)w * NC;
    float s = 0.f;
    #pragma unroll
    for (int q = 0; q < 16; ++q) {
        int qq = q * 64 + l;
        float cv = (qq < 512) ? h[b * CI + qq] : x_face[(size_t)b * 512 + qq - 512];
        s += wr[qq] * cv;
    }
    s = wred_sum(s);
    if (l == 0) out[b * 2 + w] = s + b2[w];
}

extern "C" void kernel_launch(void* const* d_in, const int* in_sizes, int n_in,
                              void* d_out, int out_size, void* d_ws, size_t ws_size,
                              hipStream_t stream) {
    const float* x_body = (const float*)d_in[0];
    const float* x_face = (const float*)d_in[1];
    const float* Wg  = (const float*)d_in[2];
    const float* bg  = (const float*)d_in[3];
    const float* Wth = (const float*)d_in[4];
    const float* bth = (const float*)d_in[5];
    const float* Wph = (const float*)d_in[6];
    const float* bph = (const float*)d_in[7];
    const float* Ww  = (const float*)d_in[8];
    const float* bw  = (const float*)d_in[9];
    const float* gamma = (const float*)d_in[10];
    const float* beta  = (const float*)d_in[11];
    const float* mean  = (const float*)d_in[12];
    const float* var   = (const float*)d_in[13];
    const float* W1 = (const float*)d_in[14];
    const float* b1 = (const float*)d_in[15];
    const float* W2 = (const float*)d_in[16];
    const float* b2 = (const float*)d_in[17];
    (void)in_sizes; (void)n_in; (void)out_size; (void)ws_size;

    char* ws = (char*)d_ws;
    u16* xbT   = (u16*)(ws + OFF_XBT);
    u16* Wcat  = (u16*)(ws + OFF_WCAT);
    u16* proj  = (u16*)(ws + OFF_PROJ);
    float* abar = (float*)(ws + OFF_ABAR);
    float* xbar = (float*)(ws + OFF_XBAR);
    float* ybar = (float*)(ws + OFF_YBAR);   // reuses xbT region (dead after k_gemm)
    float* pooled = (float*)(ws + OFF_POOL);
    float* hbuf = (float*)(ws + OFF_H);

    // zero the atomic accumulators (abar + xbar are contiguous)
    hipMemsetAsync(ws + OFF_ABAR, 0, 100352 + 131072, stream);

    k_cast_w<<<1536, 256, 0, stream>>>(Wth, Wph, Wg, Wcat);
    k_tcast<<<dim3(25, 32, 32), 256, 0, stream>>>(x_body, xbT, xbar);
    k_gemm<<<2688, 256, 0, stream>>>(xbT, Wcat, bth, bph, bg, proj);
    // xbT now dead; zero the ybar accumulator living in its space
    hipMemsetAsync(ws + OFF_YBAR, 0, 65536, stream);
    k_attn<<<800, 256, 0, stream>>>(proj, abar);
    k_ybar<<<dim3(16, 32), 256, 0, stream>>>(proj, abar, ybar);
    k_pooled<<<dim3(8, 32), 256, 0, stream>>>(ybar, xbar, Ww, bw,
                                              gamma, beta, mean, var, pooled);
    k_fc1<<<dim3(8, 32), 256, 0, stream>>>(pooled, W1, b1, hbuf);
    k_fc2<<<32, 128, 0, stream>>>(hbuf, x_face, W2, b2, (float*)d_out);
}